// Round 2
// baseline (15734.052 us; speedup 1.0000x reference)
//
#include <hip/hip_runtime.h>
#include <stdint.h>

#define SLEN 4096
#define EDIM 256
#define HD 256
#define G4 1024   // 4*HD
#define KT 20
#define START_ID 18
#define STOP_ID 19

// MFMA tiling for k_lstm: 1024 gate-rows = 64 M-tiles of 16; K=256 = 8 kwin of 32.
// 16 waves, 4 tiles/wave -> 32 (tile,kwin) A-frags (uint4) per thread:
// 23 in VGPRs, 9 in LDS.
#define NT 64
#define TPW 4
#define KW 8
#define NRP 23
#define NLP 9
// LDS: h dbuf 2*256 fp16 = 1KB @0 | zx dbuf 2*1024 f32 = 8KB @1024 | tail @9216
#define LSTM_LDS_BYTES (1024 + 8192 + NLP * 1024 * 16)   // 156672 <= 160K

typedef _Float16 half_t;
typedef _Float16 half2_t __attribute__((ext_vector_type(2)));
typedef _Float16 half8 __attribute__((ext_vector_type(8)));
typedef float f32x4 __attribute__((ext_vector_type(4)));

__device__ __forceinline__ float fsig(float x) { return 1.f / (1.f + __expf(-x)); }
__device__ __forceinline__ float ftanh(float x) { return 1.f - 2.f / (__expf(2.f * x) + 1.f); }

// row ordering for MFMA path: global row r = unit*4 + gate (gate 0..3 = i,f,g,o),
// original torch row = gate*256 + unit.

// ---------------- prep: transpose w_ih into [d][e][o] (o = original row order) ----------------
__global__ __launch_bounds__(256) void k_transpose_ih(const float* __restrict__ wf,
                                                      const float* __restrict__ wb,
                                                      float* __restrict__ wT) {
    __shared__ float tile[32][33];
    int d = blockIdx.z;
    const float* w = d ? wb : wf;
    int ob = blockIdx.x * 32;  // over 1024 rows
    int eb = blockIdx.y * 32;  // over 256 cols
    int tx = threadIdx.x & 31, ty = threadIdx.x >> 5;
#pragma unroll
    for (int r = 0; r < 32; r += 8)
        tile[ty + r][tx] = w[(long)(ob + ty + r) * EDIM + eb + tx];
    __syncthreads();
    float* dst = wT + (long)d * EDIM * G4;
#pragma unroll
    for (int r = 0; r < 32; r += 8)
        dst[(long)(eb + ty + r) * G4 + ob + tx] = tile[tx][ty + r];
}

// ---------------- prep: pack w_hh into fp16 MFMA A-fragments ----------------
// A-frag layout (16x16x32): lane l holds row (l&15), k = kw*32 + (l>>4)*8 + e  (e=0..7).
// apack uint4 index: ((d*64 + T)*8 + kw)*64 + l
__global__ __launch_bounds__(256) void k_pack_mfma(const float* __restrict__ whf,
                                                   const float* __restrict__ whb,
                                                   uint4* __restrict__ apack) {
    int gid = blockIdx.x * 256 + threadIdx.x;   // 0..65535
    int d = gid >> 15;
    int rem = gid & 32767;
    int T = rem >> 9;           // 0..63
    int kw = (rem >> 6) & 7;
    int l = rem & 63;
    const float* W = d ? whb : whf;
    int r = T * 16 + (l & 15);
    int orow = (r & 3) * 256 + (r >> 2);   // gate*256 + unit
    int kbase = kw * 32 + (l >> 4) * 8;
    uint32_t q[4];
#pragma unroll
    for (int dw = 0; dw < 4; dw++) {
        half2_t p = {(half_t)W[(long)orow * HD + kbase + 2 * dw],
                     (half_t)W[(long)orow * HD + kbase + 2 * dw + 1]};
        q[dw] = __builtin_bit_cast(uint32_t, p);
    }
    apack[gid] = make_uint4(q[0], q[1], q[2], q[3]);
}

// ---------------- input projections: zxp[d][s][unit*4+gate] = (x_s @ w_ih^T + b) ----------------
__global__ __launch_bounds__(256) void k_zx(const int* __restrict__ sentence,
                                            const float* __restrict__ embed,
                                            const float* __restrict__ wT,
                                            const float* __restrict__ bf,
                                            const float* __restrict__ bb,
                                            float* __restrict__ zxp) {
    int d = blockIdx.y;
    int s0 = blockIdx.x * 16;
    const float* bias = d ? bb : bf;
    __shared__ float xbuf[16][EDIM];
    int u = threadIdx.x;   // unit 0..255
    for (int r = 0; r < 16; r++) {
        int row = sentence[s0 + r];
        xbuf[r][u] = embed[(long)row * EDIM + u];
    }
    __syncthreads();
    const float* wTd = wT + (long)d * EDIM * G4;
    float4 a[16];
    float4 bv = make_float4(bias[u], bias[256 + u], bias[512 + u], bias[768 + u]);
#pragma unroll
    for (int r = 0; r < 16; r++) a[r] = bv;
    for (int e = 0; e < EDIM; e += 4) {
        float w0[4], w1[4], w2[4], w3[4];
#pragma unroll
        for (int k = 0; k < 4; k++) {
            w0[k] = wTd[(long)(e + k) * G4 + u];
            w1[k] = wTd[(long)(e + k) * G4 + 256 + u];
            w2[k] = wTd[(long)(e + k) * G4 + 512 + u];
            w3[k] = wTd[(long)(e + k) * G4 + 768 + u];
        }
#pragma unroll
        for (int r = 0; r < 16; r++) {
            float4 x4 = *(const float4*)&xbuf[r][e];
            float xv[4] = {x4.x, x4.y, x4.z, x4.w};
#pragma unroll
            for (int k = 0; k < 4; k++) {
                a[r].x += w0[k] * xv[k];
                a[r].y += w1[k] * xv[k];
                a[r].z += w2[k] * xv[k];
                a[r].w += w3[k] * xv[k];
            }
        }
    }
#pragma unroll
    for (int r = 0; r < 16; r++)
        *(float4*)&zxp[(long)(d * SLEN + s0 + r) * G4 + u * 4] = a[r];
}

// ---------------- the serial BiLSTM via MFMA: 2 blocks (one per direction) ----------------
// z[1024] = W_hh h + zx via mfma_f32_16x16x32_f16 with h REPLICATED across all 16 B-cols:
// every column of D is identical, so each lane's 4 acc regs = the (i,f,g,o) quad of
// unit u = 16*w + 4*i + q (C layout: col=l&15, row=(l>>4)*4+reg).  No gate shuffles.
__global__ __launch_bounds__(1024, 4) void k_lstm(const float* __restrict__ zxp,
                                                  const uint4* __restrict__ apack,
                                                  const float* __restrict__ h0,
                                                  const float* __restrict__ c0,
                                                  float* __restrict__ hs) {
    extern __shared__ char smem[];
    half_t* hbuf = (half_t*)smem;                // [2][256] fp16
    float* zxl = (float*)(smem + 1024);          // [2][1024] f32
    uint4* tail = (uint4*)(smem + 9216);         // [NLP][1024]

    int d = blockIdx.x;
    int t = threadIdx.x;
    int l = t & 63;
    int w = t >> 6;        // wave 0..15, owns tiles 4w..4w+3 (units 16w..16w+15)
    int q = l >> 4;        // 0..3

    // load A-fragments: pairs p = i*8+kw; p<NRP in regs, rest staged to LDS
    const uint4* apd = apack + ((long)d * NT + 4 * w) * KW * 64 + l;
    uint4 areg[NRP];
#pragma unroll
    for (int p = 0; p < NRP; p++) areg[p] = apd[p * 64];
#pragma unroll
    for (int p = 0; p < NLP; p++) tail[p * 1024 + t] = apd[(NRP + p) * 64];

    // cell state for this lane's 4 units (redundant across the 16 lanes of group q —
    // bit-identical since all B-columns are equal)
    float c[TPW];
#pragma unroll
    for (int i = 0; i < TPW; i++) c[i] = c0[d * HD + 16 * w + 4 * i + q];

    if (t < 128) {
        half2_t p = {(half_t)h0[d * HD + 2 * t], (half_t)h0[d * HD + 2 * t + 1]};
        ((uint32_t*)hbuf)[t] = __builtin_bit_cast(uint32_t, p);
    }
    const float* zxd = zxp + (long)d * SLEN * G4;
    int sx0 = d ? (SLEN - 1) : 0;
    if (t < 256) *(float4*)&zxl[t * 4] = *(const float4*)&zxd[(long)sx0 * G4 + t * 4];
    __syncthreads();

    float* hsd = hs + (long)d * SLEN * HD;

    for (int s = 0; s < SLEN; s++) {
        const int p = s & 1;
        // acc init = zx quad for this lane's rows (16-way broadcast ds_read_b128)
        f32x4 acc[TPW];
#pragma unroll
        for (int i = 0; i < TPW; i++)
            acc[i] = *(const f32x4*)&zxl[p * 1024 + (4 * w + i) * 16 + q * 4];

        // prefetch next step's zx slice into regs (waves 0..3), written to LDS at step end
        float4 zxn;
        if (t < 256 && s + 1 < SLEN) {
            int sxn = d ? (SLEN - 2 - s) : (s + 1);
            zxn = *(const float4*)&zxd[(long)sxn * G4 + t * 4];
        }

        const half_t* hb = hbuf + p * 256;
#pragma unroll
        for (int kw = 0; kw < KW; kw++) {
            // B-frag: h replicated across columns -> lane needs h[kw*32 + q*8 .. +7]
            half8 bfrag = *(const half8*)(hb + kw * 32 + q * 8);
#pragma unroll
            for (int i = 0; i < TPW; i++) {
                const int pp = i * KW + kw;
                uint4 av = (pp < NRP) ? areg[pp] : tail[(pp - NRP) * 1024 + t];
                acc[i] = __builtin_amdgcn_mfma_f32_16x16x32_f16(
                    __builtin_bit_cast(half8, av), bfrag, acc[i], 0, 0, 0);
            }
        }

        // activations: acc[i] = (z_i, z_f, z_g, z_o) of unit 16w+4i+q
        float hv[TPW];
#pragma unroll
        for (int i = 0; i < TPW; i++) {
            float ig = fsig(acc[i][0]), fg = fsig(acc[i][1]);
            float gg = ftanh(acc[i][2]), og = fsig(acc[i][3]);
            c[i] = fg * c[i] + ig * gg;
            hv[i] = og * ftanh(c[i]);
        }

        // writers: lane with (l&15)==i writes unit 16w+4i+q (static-index select)
        int i0 = l & 15;
        float hvw = (i0 == 0) ? hv[0] : (i0 == 1) ? hv[1] : (i0 == 2) ? hv[2] : hv[3];
        if (i0 < TPW) {
            int u = 16 * w + 4 * i0 + q;
            int sx = d ? (SLEN - 1 - s) : s;
            hsd[(long)sx * HD + u] = hvw;
            hbuf[(p ^ 1) * 256 + u] = (half_t)hvw;
        }
        if (t < 256 && s + 1 < SLEN) *(float4*)&zxl[(p ^ 1) * 1024 + t * 4] = zxn;
        __syncthreads();
    }
}

// ---------------- feats[s][k] = emitW[k] . [h_fwd[s], h_bwd[s]] + emit_b[k] ----------------
__global__ __launch_bounds__(192) void k_feats(const float* __restrict__ hs,
                                               const float* __restrict__ emitW,
                                               const float* __restrict__ emitb,
                                               float* __restrict__ feats) {
    __shared__ float wb[KT][516];
    __shared__ float hb[8][516];
    int tid = threadIdx.x;
    int s0 = blockIdx.x * 8;
    for (int idx = tid; idx < KT * 512; idx += 192) {
        wb[idx >> 9][idx & 511] = emitW[idx];
    }
    for (int idx = tid; idx < 8 * 512; idx += 192) {
        int sl = idx >> 9, jj = idx & 511;
        float v = (jj < 256) ? hs[(long)(s0 + sl) * HD + jj]
                             : hs[(long)(SLEN + s0 + sl) * HD + (jj - 256)];
        hb[sl][jj] = v;
    }
    __syncthreads();
    if (tid < 160) {
        int sl = tid / KT, k = tid % KT;
        float acc = emitb[k];
        for (int jj = 0; jj < 512; jj += 4) {
            float4 wv = *(const float4*)&wb[k][jj];
            float4 hv = *(const float4*)&hb[sl][jj];
            acc += wv.x * hv.x + wv.y * hv.y + wv.z * hv.z + wv.w * hv.w;
        }
        feats[(long)(s0 + sl) * KT + k] = acc;
    }
}

// ---------------- gold path score -> out[1] ----------------
__global__ __launch_bounds__(256) void k_gold(const float* __restrict__ feats,
                                              const int* __restrict__ tags,
                                              const float* __restrict__ trans,
                                              float* __restrict__ out) {
    __shared__ float red[256];
    int tid = threadIdx.x;
    float local = 0.f;
    for (int s2 = tid; s2 < SLEN; s2 += 256) {
        int cur = tags[s2];
        int prev = s2 ? tags[s2 - 1] : START_ID;
        local += trans[cur * KT + prev] + feats[(long)s2 * KT + cur];
    }
    red[tid] = local;
    __syncthreads();
    for (int off = 128; off; off >>= 1) {
        if (tid < off) red[tid] += red[tid + off];
        __syncthreads();
    }
    if (tid == 0) out[1] = red[0] + trans[STOP_ID * KT + tags[SLEN - 1]];
}

// ---------------- CRF: chunk of 16 step-matrices -> one 20x20 log-space matrix ----------------
__global__ __launch_bounds__(512) void k_crf_chunk(const float* __restrict__ feats,
                                                   const float* __restrict__ trans,
                                                   float* __restrict__ mats) {
    __shared__ float T[KT][KT + 1];
    __shared__ float fb[16][KT];
    __shared__ float cur[2][KT][KT + 1];
    int tid = threadIdx.x;
    int t0 = blockIdx.x * 16;
    if (tid < KT * KT) T[tid / KT][tid % KT] = trans[tid];
    for (int idx = tid; idx < 16 * KT; idx += 512) fb[idx / KT][idx % KT] = feats[(long)t0 * KT + idx];
    __syncthreads();
    int i = tid / KT, jc = tid % KT;
    bool act = tid < KT * KT;
    if (act) cur[0][i][jc] = T[i][jc] + fb[0][i];
    __syncthreads();
    for (int m = 1; m < 16; m++) {
        int p = (m - 1) & 1;
        float nv = 0.f;
        if (act) {
            float vs[KT], vmax = -1e30f;
#pragma unroll
            for (int k = 0; k < KT; k++) { vs[k] = T[i][k] + cur[p][k][jc]; vmax = fmaxf(vmax, vs[k]); }
            float sum = 0.f;
#pragma unroll
            for (int k = 0; k < KT; k++) sum += __expf(vs[k] - vmax);
            nv = fb[m][i] + vmax + __logf(sum);
        }
        if (act) cur[p ^ 1][i][jc] = nv;
        __syncthreads();
    }
    if (act) mats[(long)blockIdx.x * (KT * KT) + tid] = cur[1][i][jc];
}

// ---------------- CRF: combine per_block consecutive matrices (left-applied) ----------------
__global__ __launch_bounds__(512) void k_crf_combine(const float* __restrict__ in,
                                                     float* __restrict__ out_mats,
                                                     int per_block,
                                                     const float* __restrict__ trans,
                                                     float* __restrict__ d_out_ptr,
                                                     int finalize) {
    __shared__ float A[KT][KT + 1];
    __shared__ float cur[2][KT][KT + 1];
    int tid = threadIdx.x;
    int b = blockIdx.x;
    int i = tid / KT, jc = tid % KT;
    bool act = tid < KT * KT;
    const float* base = in + (long)b * per_block * (KT * KT);
    if (act) cur[0][i][jc] = base[tid];
    __syncthreads();
    for (int m = 1; m < per_block; m++) {
        int p = (m - 1) & 1;
        if (act) A[i][jc] = base[(long)m * KT * KT + tid];
        __syncthreads();
        float nv = 0.f;
        if (act) {
            float vs[KT], vmax = -1e30f;
#pragma unroll
            for (int k = 0; k < KT; k++) { vs[k] = A[i][k] + cur[p][k][jc]; vmax = fmaxf(vmax, vs[k]); }
            float sum = 0.f;
#pragma unroll
            for (int k = 0; k < KT; k++) sum += __expf(vs[k] - vmax);
            nv = vmax + __logf(sum);
        }
        if (act) cur[p ^ 1][i][jc] = nv;
        __syncthreads();
    }
    int fbuf = (per_block - 1) & 1;
    if (!finalize) {
        if (act) out_mats[(long)b * KT * KT + tid] = cur[fbuf][i][jc];
        return;
    }
    if (tid == 0) {
        float fv[KT];
        for (int ii = 0; ii < KT; ii++) {
            float vs[KT], vmax = -1e30f;
            for (int k = 0; k < KT; k++) {
                float v = cur[fbuf][ii][k] + (k == START_ID ? 0.f : -10000.f);
                vs[k] = v;
                vmax = fmaxf(vmax, v);
            }
            float sum = 0.f;
            for (int k = 0; k < KT; k++) sum += __expf(vs[k] - vmax);
            fv[ii] = vmax + __logf(sum);
        }
        float vs2[KT], vmax = -1e30f;
        for (int ii = 0; ii < KT; ii++) {
            float v = fv[ii] + trans[STOP_ID * KT + ii];
            vs2[ii] = v;
            vmax = fmaxf(vmax, v);
        }
        float sum = 0.f;
        for (int ii = 0; ii < KT; ii++) sum += __expf(vs2[ii] - vmax);
        d_out_ptr[0] = vmax + __logf(sum);
    }
}

extern "C" void kernel_launch(void* const* d_in, const int* in_sizes, int n_in,
                              void* d_out, int out_size, void* d_ws, size_t ws_size,
                              hipStream_t stream) {
    const int* sentence = (const int*)d_in[0];
    const int* tags = (const int*)d_in[1];
    const float* embed = (const float*)d_in[2];
    const float* w_ih_f = (const float*)d_in[3];
    const float* w_hh_f = (const float*)d_in[4];
    const float* b_f = (const float*)d_in[5];
    const float* w_ih_b = (const float*)d_in[6];
    const float* w_hh_b = (const float*)d_in[7];
    const float* b_b = (const float*)d_in[8];
    const float* h0 = (const float*)d_in[9];
    const float* c0 = (const float*)d_in[10];
    const float* emit_W = (const float*)d_in[11];
    const float* emit_b = (const float*)d_in[12];
    const float* transition = (const float*)d_in[13];
    float* out = (float*)d_out;

    char* ws = (char*)d_ws;
    float* zxp = (float*)(ws + 0);                       // 2*4096*1024 f32 = 32 MB
    float* hs = (float*)(ws + 33554432);                 // 2*4096*256 f32  = 8 MB
    float* wT = (float*)(ws + 41943040);                 // 2*256*1024 f32  = 2 MB
    uint4* apack = (uint4*)(ws + 44040192);              // 65536 uint4 = 1 MB
    float* feats = (float*)(ws + 45088768);              // 4096*20 f32
    float* mats = (float*)(ws + 45416448);               // 256*400 f32
    float* mats2 = (float*)(ws + 45826048);              // 16*400 f32

    // opt-in to >64KB dynamic LDS for k_lstm (idempotent host call, not a stream op)
    (void)hipFuncSetAttribute((const void*)k_lstm,
                              hipFuncAttributeMaxDynamicSharedMemorySize,
                              LSTM_LDS_BYTES);

    k_transpose_ih<<<dim3(32, 8, 2), 256, 0, stream>>>(w_ih_f, w_ih_b, wT);
    k_pack_mfma<<<dim3(256), 256, 0, stream>>>(w_hh_f, w_hh_b, apack);
    k_zx<<<dim3(256, 2), 256, 0, stream>>>(sentence, embed, wT, b_f, b_b, zxp);
    k_lstm<<<dim3(2), 1024, LSTM_LDS_BYTES, stream>>>(zxp, apack, h0, c0, hs);
    k_feats<<<dim3(512), 192, 0, stream>>>(hs, emit_W, emit_b, feats);
    k_gold<<<dim3(1), 256, 0, stream>>>(feats, tags, transition, out);
    k_crf_chunk<<<dim3(256), 512, 0, stream>>>(feats, transition, mats);
    k_crf_combine<<<dim3(16), 512, 0, stream>>>(mats, mats2, 16, transition, out, 0);
    k_crf_combine<<<dim3(1), 512, 0, stream>>>(mats2, nullptr, 16, transition, out, 1);
}

// Round 3
// 8573.419 us; speedup vs baseline: 1.8352x; 1.8352x over previous
//
#include <hip/hip_runtime.h>
#include <stdint.h>

#define SLEN 4096
#define EDIM 256
#define HD 256
#define G4 1024   // 4*HD
#define KT 20
#define START_ID 18
#define STOP_ID 19

// K-split weight layout for k_lstm: each thread owns 2 gate-rows over half of K.
// Per thread 128 weight dwords = 32 chunks of 4 dwords: chunk cc<16 -> rowA (gate gA),
// cc>=16 -> rowB (gate gA+2), K window = kh*128 + (cc&15)*8 .. +7.
// Dwords 0..91 (rowA all + rowB chunks 0..6) in VGPRs; rowB chunks 7..15 (9 uint4) in LDS.
#define NLC 9           // LDS tail chunks (uint4 per thread)
#define LSTM_LDS_BYTES (1024 + 1024 * NLC * 16)   // h dbuf (2*512B) + tail weights

typedef _Float16 half_t;
typedef _Float16 half2_t __attribute__((ext_vector_type(2)));

__device__ __forceinline__ float dot2(uint32_t w, uint32_t h, float acc) {
#if __has_builtin(__builtin_amdgcn_fdot2)
    return __builtin_amdgcn_fdot2(__builtin_bit_cast(half2_t, w),
                                  __builtin_bit_cast(half2_t, h), acc, false);
#else
    half2_t wv = __builtin_bit_cast(half2_t, w);
    half2_t hv = __builtin_bit_cast(half2_t, h);
    acc += (float)wv.x * (float)hv.x;
    acc += (float)wv.y * (float)hv.y;
    return acc;
#endif
}

__device__ __forceinline__ float fsig(float x) { return 1.f / (1.f + __expf(-x)); }
__device__ __forceinline__ float ftanh(float x) { return 1.f - 2.f / (__expf(2.f * x) + 1.f); }

// k_lstm thread mapping (K-split):
//   w = t>>6, l = t&63, kh = l>>5 (K half), gA = (l>>4)&1, lj = l&15, j = 16w+lj
//   thread partial-dots rows (gA*256+j) and ((gA+2)*256+j) over K in [kh*128, kh*128+128)
//   buddy lane l^32 has the other K half of the SAME rows -> one shfl_xor(32) combines.

// ---------------- prep: transpose w_ih into [d][e][o] ----------------
__global__ __launch_bounds__(256) void k_transpose_ih(const float* __restrict__ wf,
                                                      const float* __restrict__ wb,
                                                      float* __restrict__ wT) {
    __shared__ float tile[32][33];
    int d = blockIdx.z;
    const float* w = d ? wb : wf;
    int ob = blockIdx.x * 32;  // over 1024 rows
    int eb = blockIdx.y * 32;  // over 256 cols
    int tx = threadIdx.x & 31, ty = threadIdx.x >> 5;
#pragma unroll
    for (int r = 0; r < 32; r += 8)
        tile[ty + r][tx] = w[(long)(ob + ty + r) * EDIM + eb + tx];
    __syncthreads();
    float* dst = wT + (long)d * EDIM * G4;
#pragma unroll
    for (int r = 0; r < 32; r += 8)
        dst[(long)(eb + ty + r) * G4 + ob + tx] = tile[tx][ty + r];
}

// ---------------- prep: pack w_hh to fp16 in K-split lstm thread order ----------------
__global__ __launch_bounds__(1024) void k_pack_hh(const float* __restrict__ whf,
                                                  const float* __restrict__ whb,
                                                  uint32_t* __restrict__ wpack,
                                                  uint32_t* __restrict__ wtail) {
    int d = blockIdx.y;
    const float* W = d ? whb : whf;
    int t = threadIdx.x;
    int l = t & 63;
    int w = t >> 6;
    int kh = l >> 5;
    int gA = (l >> 4) & 1;
    int j = (w << 4) | (l & 15);
    int rowA = gA * 256 + j;
    int rowB = (gA + 2) * 256 + j;
    int bx = blockIdx.x;  // 0..91 -> wpack dwords, 92..100 -> wtail chunks

    auto packdw = [&](int dd) -> uint32_t {
        int cc = dd >> 2, qq = dd & 3;
        int row = (cc < 16) ? rowA : rowB;
        int k = kh * 128 + (cc & 15) * 8 + qq * 2;
        half2_t p = {(half_t)W[(long)row * HD + k], (half_t)W[(long)row * HD + k + 1]};
        return __builtin_bit_cast(uint32_t, p);
    };

    if (bx < 92) {
        wpack[(d * 92 + bx) * 1024 + t] = packdw(bx);
    } else {
        int cb = bx - 92;
        uint4* dst = (uint4*)wtail;
        dst[(d * NLC + cb) * 1024 + t] = make_uint4(packdw(92 + cb * 4), packdw(93 + cb * 4),
                                                    packdw(94 + cb * 4), packdw(95 + cb * 4));
    }
}

// ---------------- input projections: zxp[d][s][w*64 + g*16 + (j&15)] ----------------
__global__ __launch_bounds__(256) void k_zx(const int* __restrict__ sentence,
                                            const float* __restrict__ embed,
                                            const float* __restrict__ wT,
                                            const float* __restrict__ bf,
                                            const float* __restrict__ bb,
                                            float* __restrict__ zxp) {
    int d = blockIdx.y;
    int s0 = blockIdx.x * 16;
    const float* bias = d ? bb : bf;
    __shared__ float xbuf[16][EDIM];
    int tid = threadIdx.x;
    for (int r = 0; r < 16; r++) {
        int row = sentence[s0 + r];
        xbuf[r][tid] = embed[(long)row * EDIM + tid];
    }
    __syncthreads();
    const float* wTd = wT + (long)d * EDIM * G4;
    for (int og = 0; og < 4; og++) {
        float acc[16];
#pragma unroll
        for (int r = 0; r < 16; r++) acc[r] = 0.f;
        int o = og * 256 + tid;
        for (int e = 0; e < EDIM; e += 4) {
            float w0 = wTd[(long)(e + 0) * G4 + o];
            float w1 = wTd[(long)(e + 1) * G4 + o];
            float w2 = wTd[(long)(e + 2) * G4 + o];
            float w3 = wTd[(long)(e + 3) * G4 + o];
#pragma unroll
            for (int r = 0; r < 16; r++) {
                float4 x4 = *(const float4*)&xbuf[r][e];
                acc[r] += w0 * x4.x + w1 * x4.y + w2 * x4.z + w3 * x4.w;
            }
        }
        float bv = bias[o];
        int tB = ((tid >> 4) << 6) | (og << 4) | (tid & 15);
#pragma unroll
        for (int r = 0; r < 16; r++)
            zxp[(long)(d * SLEN + s0 + r) * G4 + tB] = acc[r] + bv;
    }
}

// ---------------- the serial BiLSTM: 2 blocks (one per direction) ----------------
// K-split: wave reads only 16 h-chunks/step (lane-dependent addr covers both K halves),
// halving the dominant DS-pipe cost vs the 32-read broadcast version.
__global__ __launch_bounds__(1024, 4) void k_lstm(const float* __restrict__ zxp,
                                                  const uint32_t* __restrict__ wpack,
                                                  const uint4* __restrict__ wtail,
                                                  const float* __restrict__ h0,
                                                  const float* __restrict__ c0,
                                                  float* __restrict__ hs) {
    extern __shared__ char smem[];
    uint4* h2q = (uint4*)smem;              // [2][32] uint4 = 2 x 256 fp16 h
    half_t* h2h = (half_t*)smem;            // [buf*256 + j]
    uint4* tail = (uint4*)(smem + 1024);    // [NLC][1024] per-thread tail weights

    int d = blockIdx.x;
    int t = threadIdx.x;
    int l = t & 63;
    int w = t >> 6;
    int kh = l >> 5;
    int gA = (l >> 4) & 1;
    int lj = l & 15;
    int j = (w << 4) | lj;

    uint32_t wreg[92];
#pragma unroll
    for (int kk = 0; kk < 92; kk++) wreg[kk] = wpack[(d * 92 + kk) * 1024 + t];

    // stage tail weights into LDS (per-thread, lane-consecutive 16B -> conflict-free)
#pragma unroll
    for (int cb = 0; cb < NLC; cb++)
        tail[cb * 1024 + t] = wtail[(d * NLC + cb) * 1024 + t];

    float c = c0[d * HD + j];
    if (t < 128) {
        half2_t p = {(half_t)h0[d * HD + 2 * t], (half_t)h0[d * HD + 2 * t + 1]};
        ((uint32_t*)h2q)[t] = __builtin_bit_cast(uint32_t, p);
    }
    __syncthreads();

    const float* zxd = zxp + (long)d * SLEN * G4;
    float* hsd = hs + (long)d * SLEN * HD + j;
    int colA = (w << 6) | (gA << 4) | lj;   // zx index of rowA; rowB is +32

    // software-pipelined zx reads (hides LLC latency)
    int sx0 = d ? (SLEN - 1) : 0;
    float zxAn = zxd[(long)sx0 * G4 + colA];
    float zxBn = zxd[(long)sx0 * G4 + colA + 32];

    for (int s = 0; s < SLEN; s++) {
        const int p = s & 1;
        float zxA = zxAn, zxB = zxBn;
        if (s + 1 < SLEN) {
            int sxn = d ? (SLEN - 2 - s) : (s + 1);
            zxAn = zxd[(long)sxn * G4 + colA];
            zxBn = zxd[(long)sxn * G4 + colA + 32];
        }

        const uint4* hq = h2q + p * 32 + kh * 16;   // this lane's K-half chunks
        float pA0 = 0.f, pA1 = 0.f, pB0 = 0.f, pB1 = 0.f;
#pragma unroll
        for (int cc = 0; cc < 16; cc++) {
            uint4 hv = hq[cc];
            pA0 = dot2(wreg[4 * cc + 0], hv.x, pA0);
            pA1 = dot2(wreg[4 * cc + 1], hv.y, pA1);
            pA0 = dot2(wreg[4 * cc + 2], hv.z, pA0);
            pA1 = dot2(wreg[4 * cc + 3], hv.w, pA1);
            if (cc < 7) {
                pB0 = dot2(wreg[64 + 4 * cc + 0], hv.x, pB0);
                pB1 = dot2(wreg[64 + 4 * cc + 1], hv.y, pB1);
                pB0 = dot2(wreg[64 + 4 * cc + 2], hv.z, pB0);
                pB1 = dot2(wreg[64 + 4 * cc + 3], hv.w, pB1);
            } else {
                uint4 tw = tail[(cc - 7) * 1024 + t];
                pB0 = dot2(tw.x, hv.x, pB0);
                pB1 = dot2(tw.y, hv.y, pB1);
                pB0 = dot2(tw.z, hv.z, pB0);
                pB1 = dot2(tw.w, hv.w, pB1);
            }
        }

        // combine K halves with buddy lane l^32 (same rows, other half)
        float sA = pA0 + pA1;
        float sB = pB0 + pB1;
        sA += __shfl_xor(sA, 32, 64);
        sB += __shfl_xor(sB, 32, 64);
        float zAf = sA + zxA;   // full z of row (gA,  j)
        float zBf = sB + zxB;   // full z of row (gA+2, j)

        // gather the 4 gates of unit j: lane lj holds (i,g), lane lj+16 holds (f,o)
        float zi = __shfl(zAf, lj, 64);
        float zf = __shfl(zAf, lj + 16, 64);
        float zg = __shfl(zBf, lj, 64);
        float zo = __shfl(zBf, lj + 16, 64);

        float ig = fsig(zi), fg = fsig(zf), og = fsig(zo);
        float gg = ftanh(zg);
        c = fg * c + ig * gg;
        float hval = og * ftanh(c);
        if (l < 16) {
            int sx = d ? (SLEN - 1 - s) : s;
            hsd[(long)sx * HD] = hval;
            h2h[((p ^ 1) << 8) + j] = (half_t)hval;
        }
        __syncthreads();
    }
}

// ---------------- feats[s][k] = emitW[k] . [h_fwd[s], h_bwd[s]] + emit_b[k] ----------------
__global__ __launch_bounds__(192) void k_feats(const float* __restrict__ hs,
                                               const float* __restrict__ emitW,
                                               const float* __restrict__ emitb,
                                               float* __restrict__ feats) {
    __shared__ float wb[KT][516];
    __shared__ float hb[8][516];
    int tid = threadIdx.x;
    int s0 = blockIdx.x * 8;
    for (int idx = tid; idx < KT * 512; idx += 192) {
        wb[idx >> 9][idx & 511] = emitW[idx];
    }
    for (int idx = tid; idx < 8 * 512; idx += 192) {
        int sl = idx >> 9, jj = idx & 511;
        float v = (jj < 256) ? hs[(long)(s0 + sl) * HD + jj]
                             : hs[(long)(SLEN + s0 + sl) * HD + (jj - 256)];
        hb[sl][jj] = v;
    }
    __syncthreads();
    if (tid < 160) {
        int sl = tid / KT, k = tid % KT;
        float acc = emitb[k];
        for (int jj = 0; jj < 512; jj += 4) {
            float4 wv = *(const float4*)&wb[k][jj];
            float4 hv = *(const float4*)&hb[sl][jj];
            acc += wv.x * hv.x + wv.y * hv.y + wv.z * hv.z + wv.w * hv.w;
        }
        feats[(long)(s0 + sl) * KT + k] = acc;
    }
}

// ---------------- gold path score -> out[1] ----------------
__global__ __launch_bounds__(256) void k_gold(const float* __restrict__ feats,
                                              const int* __restrict__ tags,
                                              const float* __restrict__ trans,
                                              float* __restrict__ out) {
    __shared__ float red[256];
    int tid = threadIdx.x;
    float local = 0.f;
    for (int s2 = tid; s2 < SLEN; s2 += 256) {
        int cur = tags[s2];
        int prev = s2 ? tags[s2 - 1] : START_ID;
        local += trans[cur * KT + prev] + feats[(long)s2 * KT + cur];
    }
    red[tid] = local;
    __syncthreads();
    for (int off = 128; off; off >>= 1) {
        if (tid < off) red[tid] += red[tid + off];
        __syncthreads();
    }
    if (tid == 0) out[1] = red[0] + trans[STOP_ID * KT + tags[SLEN - 1]];
}

// ---------------- CRF: chunk of 16 step-matrices -> one 20x20 log-space matrix ----------------
__global__ __launch_bounds__(512) void k_crf_chunk(const float* __restrict__ feats,
                                                   const float* __restrict__ trans,
                                                   float* __restrict__ mats) {
    __shared__ float T[KT][KT + 1];
    __shared__ float fb[16][KT];
    __shared__ float cur[2][KT][KT + 1];
    int tid = threadIdx.x;
    int t0 = blockIdx.x * 16;
    if (tid < KT * KT) T[tid / KT][tid % KT] = trans[tid];
    for (int idx = tid; idx < 16 * KT; idx += 512) fb[idx / KT][idx % KT] = feats[(long)t0 * KT + idx];
    __syncthreads();
    int i = tid / KT, jc = tid % KT;
    bool act = tid < KT * KT;
    if (act) cur[0][i][jc] = T[i][jc] + fb[0][i];
    __syncthreads();
    for (int m = 1; m < 16; m++) {
        int p = (m - 1) & 1;
        float nv = 0.f;
        if (act) {
            float vs[KT], vmax = -1e30f;
#pragma unroll
            for (int k = 0; k < KT; k++) { vs[k] = T[i][k] + cur[p][k][jc]; vmax = fmaxf(vmax, vs[k]); }
            float sum = 0.f;
#pragma unroll
            for (int k = 0; k < KT; k++) sum += __expf(vs[k] - vmax);
            nv = fb[m][i] + vmax + __logf(sum);
        }
        if (act) cur[p ^ 1][i][jc] = nv;
        __syncthreads();
    }
    if (act) mats[(long)blockIdx.x * (KT * KT) + tid] = cur[1][i][jc];
}

// ---------------- CRF: combine per_block consecutive matrices (left-applied) ----------------
__global__ __launch_bounds__(512) void k_crf_combine(const float* __restrict__ in,
                                                     float* __restrict__ out_mats,
                                                     int per_block,
                                                     const float* __restrict__ trans,
                                                     float* __restrict__ d_out_ptr,
                                                     int finalize) {
    __shared__ float A[KT][KT + 1];
    __shared__ float cur[2][KT][KT + 1];
    int tid = threadIdx.x;
    int b = blockIdx.x;
    int i = tid / KT, jc = tid % KT;
    bool act = tid < KT * KT;
    const float* base = in + (long)b * per_block * (KT * KT);
    if (act) cur[0][i][jc] = base[tid];
    __syncthreads();
    for (int m = 1; m < per_block; m++) {
        int p = (m - 1) & 1;
        if (act) A[i][jc] = base[(long)m * KT * KT + tid];
        __syncthreads();
        float nv = 0.f;
        if (act) {
            float vs[KT], vmax = -1e30f;
#pragma unroll
            for (int k = 0; k < KT; k++) { vs[k] = A[i][k] + cur[p][k][jc]; vmax = fmaxf(vmax, vs[k]); }
            float sum = 0.f;
#pragma unroll
            for (int k = 0; k < KT; k++) sum += __expf(vs[k] - vmax);
            nv = vmax + __logf(sum);
        }
        if (act) cur[p ^ 1][i][jc] = nv;
        __syncthreads();
    }
    int fbuf = (per_block - 1) & 1;
    if (!finalize) {
        if (act) out_mats[(long)b * KT * KT + tid] = cur[fbuf][i][jc];
        return;
    }
    if (tid == 0) {
        float fv[KT];
        for (int ii = 0; ii < KT; ii++) {
            float vs[KT], vmax = -1e30f;
            for (int k = 0; k < KT; k++) {
                float v = cur[fbuf][ii][k] + (k == START_ID ? 0.f : -10000.f);
                vs[k] = v;
                vmax = fmaxf(vmax, v);
            }
            float sum = 0.f;
            for (int k = 0; k < KT; k++) sum += __expf(vs[k] - vmax);
            fv[ii] = vmax + __logf(sum);
        }
        float vs2[KT], vmax = -1e30f;
        for (int ii = 0; ii < KT; ii++) {
            float v = fv[ii] + trans[STOP_ID * KT + ii];
            vs2[ii] = v;
            vmax = fmaxf(vmax, v);
        }
        float sum = 0.f;
        for (int ii = 0; ii < KT; ii++) sum += __expf(vs2[ii] - vmax);
        d_out_ptr[0] = vmax + __logf(sum);
    }
}

extern "C" void kernel_launch(void* const* d_in, const int* in_sizes, int n_in,
                              void* d_out, int out_size, void* d_ws, size_t ws_size,
                              hipStream_t stream) {
    const int* sentence = (const int*)d_in[0];
    const int* tags = (const int*)d_in[1];
    const float* embed = (const float*)d_in[2];
    const float* w_ih_f = (const float*)d_in[3];
    const float* w_hh_f = (const float*)d_in[4];
    const float* b_f = (const float*)d_in[5];
    const float* w_ih_b = (const float*)d_in[6];
    const float* w_hh_b = (const float*)d_in[7];
    const float* b_b = (const float*)d_in[8];
    const float* h0 = (const float*)d_in[9];
    const float* c0 = (const float*)d_in[10];
    const float* emit_W = (const float*)d_in[11];
    const float* emit_b = (const float*)d_in[12];
    const float* transition = (const float*)d_in[13];
    float* out = (float*)d_out;

    char* ws = (char*)d_ws;
    float* zxp = (float*)(ws + 0);                       // 2*4096*1024 f32 = 32 MB
    float* hs = (float*)(ws + 33554432);                 // 2*4096*256 f32  = 8 MB
    float* wT = (float*)(ws + 41943040);                 // 2*256*1024 f32  = 2 MB
    uint32_t* wpack = (uint32_t*)(ws + 44040192);        // 2*92*1024 u32 = 736 KB
    uint32_t* wtail = (uint32_t*)(ws + 44793856);        // 2*9*1024*4 u32 = 288 KB
    float* feats = (float*)(ws + 45088768);              // 4096*20 f32
    float* mats = (float*)(ws + 45416448);               // 256*400 f32
    float* mats2 = (float*)(ws + 45826048);              // 16*400 f32

    // opt-in to >64KB dynamic LDS for k_lstm (idempotent host call, not a stream op)
    (void)hipFuncSetAttribute((const void*)k_lstm,
                              hipFuncAttributeMaxDynamicSharedMemorySize,
                              LSTM_LDS_BYTES);

    k_transpose_ih<<<dim3(32, 8, 2), 256, 0, stream>>>(w_ih_f, w_ih_b, wT);
    k_pack_hh<<<dim3(101, 2), 1024, 0, stream>>>(w_hh_f, w_hh_b, wpack, wtail);
    k_zx<<<dim3(256, 2), 256, 0, stream>>>(sentence, embed, wT, b_f, b_b, zxp);
    k_lstm<<<dim3(2), 1024, LSTM_LDS_BYTES, stream>>>(zxp, wpack, (const uint4*)wtail, h0, c0, hs);
    k_feats<<<dim3(512), 192, 0, stream>>>(hs, emit_W, emit_b, feats);
    k_gold<<<dim3(1), 256, 0, stream>>>(feats, tags, transition, out);
    k_crf_chunk<<<dim3(256), 512, 0, stream>>>(feats, transition, mats);
    k_crf_combine<<<dim3(16), 512, 0, stream>>>(mats, mats2, 16, transition, out, 0);
    k_crf_combine<<<dim3(1), 512, 0, stream>>>(mats2, nullptr, 16, transition, out, 1);
}